// Round 1
// baseline (161.792 us; speedup 1.0000x reference)
//
#include <hip/hip_runtime.h>

#define TPB 256
constexpr int B_ = 8, C_ = 192, H_ = 56, W_ = 56, O_ = 384;
constexpr int HW_ = H_ * W_;          // 3136
constexpr int NOFF = 18;              // 9 taps * 2 (dy,dx)

// ---------------- K0: transpose pw_w (O,C) -> wt (C,O) ----------------
__global__ __launch_bounds__(TPB) void k_wt(const float* __restrict__ pw,
                                            float* __restrict__ wt) {
  int i = blockIdx.x * TPB + threadIdx.x;
  if (i < O_ * C_) {
    int o = i / C_, c = i - o * C_;
    wt[c * O_ + o] = pw[i];
  }
}

// ---------------- K1: depthwise 3x3, pad 1 ----------------
__global__ __launch_bounds__(TPB) void k_dw(const float* __restrict__ x,
                                            const float* __restrict__ wdw,
                                            float* __restrict__ t1) {
  int idx = blockIdx.x * TPB + threadIdx.x;
  if (idx >= B_ * C_ * HW_) return;
  int w = idx % W_;
  int h = (idx / W_) % H_;
  int c = (idx / HW_) % C_;
  const float* wp = wdw + c * 9;
  float acc = 0.f;
#pragma unroll
  for (int i = 0; i < 3; ++i) {
    int hh = h + i - 1;
    if ((unsigned)hh >= (unsigned)H_) continue;
#pragma unroll
    for (int j = 0; j < 3; ++j) {
      int ww = w + j - 1;
      if ((unsigned)ww >= (unsigned)W_) continue;
      acc += x[idx + (i - 1) * W_ + (j - 1)] * wp[i * 3 + j];
    }
  }
  t1[idx] = acc;
}

// ---------------- K2: pointwise C->18 + clip ----------------
// thread per (b, ch, 4-pixel group); 8*18*784 = 112896 threads = 441 blocks
__global__ __launch_bounds__(TPB) void k_pw18(const float* __restrict__ t1,
                                              const float* __restrict__ wpw,
                                              float* __restrict__ offp) {
  int idx = blockIdx.x * TPB + threadIdx.x;
  int q = idx % (HW_ / 4);
  int ch = (idx / (HW_ / 4)) % NOFF;
  int b = idx / (NOFF * (HW_ / 4));
  const float4* tp = (const float4*)(t1 + (size_t)b * C_ * HW_) + q;
  const float* wp = wpw + ch * C_;
  float4 acc = make_float4(0.f, 0.f, 0.f, 0.f);
  for (int c = 0; c < C_; ++c) {
    float4 v = tp[c * (HW_ / 4)];
    float wv = wp[c];
    acc.x += v.x * wv; acc.y += v.y * wv;
    acc.z += v.z * wv; acc.w += v.w * wv;
  }
  float4 r;
  r.x = fminf(fmaxf(acc.x, -1.f), 1.f);
  r.y = fminf(fmaxf(acc.y, -1.f), 1.f);
  r.z = fminf(fmaxf(acc.z, -1.f), 1.f);
  r.w = fminf(fmaxf(acc.w, -1.f), 1.f);
  float4* op = (float4*)(offp + ((size_t)b * NOFF + ch) * HW_) + q;
  *op = r;
}

// ---------------- K3: deformable sample + dcn 9-tap reduce ----------------
// block = (row-chunk of 8, channel-group of 8, b); LDS holds 8 channel
// sub-planes with zero-filled halo (rows r0-2..r0+10, cols -2..61).
__global__ __launch_bounds__(TPB) void k_deform(const float* __restrict__ x,
                                                const float* __restrict__ offp,
                                                const float* __restrict__ dcn,
                                                float* __restrict__ y1) {
  constexpr int ROWS = 8, LR = 13, LW = 64, G = 8;
  __shared__ float sx[G * LR * LW];   // 26.6 KB
  int r0 = blockIdx.x * ROWS;
  int c0 = blockIdx.y * G;
  int b = blockIdx.z;
  int tid = threadIdx.x;

  for (int t = tid; t < G * LR * LW; t += TPB) {
    int cc = t / (LR * LW);
    int rem = t - cc * (LR * LW);
    int r = rem >> 6;
    int lx = rem & 63;
    int gy = r0 - 2 + r;
    int gx = lx - 2;
    float v = 0.f;
    if ((unsigned)gy < (unsigned)H_ && (unsigned)gx < (unsigned)W_)
      v = x[(((size_t)b * C_ + c0 + cc) * H_ + gy) * W_ + gx];
    sx[t] = v;
  }
  __syncthreads();

  for (int p = tid; p < ROWS * W_; p += TPB) {
    int hl = p / W_;
    int wcol = p - hl * W_;
    int h = r0 + hl;
    const float* op = offp + (size_t)b * NOFF * HW_ + h * W_ + wcol;
    float acc[G];
#pragma unroll
    for (int cc = 0; cc < G; ++cc) acc[cc] = 0.f;
#pragma unroll
    for (int k = 0; k < 9; ++k) {
      float dy = op[(2 * k) * HW_];
      float dx = op[(2 * k + 1) * HW_];
      float ys = (float)(h + k / 3 - 1) + dy;
      float xs = (float)(wcol + k % 3 - 1) + dx;
      float y0f = floorf(ys), x0f = floorf(xs);
      float ty = ys - y0f, tx = xs - x0f;
      int y0 = (int)y0f, x0 = (int)x0f;
      float omty = 1.f - ty, omtx = 1.f - tx;
      float w00 = omty * omtx, w01 = omty * tx;
      float w10 = ty * omtx, w11 = ty * tx;
      int base = (y0 - (r0 - 2)) * LW + (x0 + 2);
#pragma unroll
      for (int cc = 0; cc < G; ++cc) {
        const float* sp = sx + cc * (LR * LW) + base;
        float v00 = sp[0], v01 = sp[1], v10 = sp[LW], v11 = sp[LW + 1];
        float s = w00 * v00 + w01 * v01 + w10 * v10 + w11 * v11;
        acc[cc] += s * dcn[(c0 + cc) * 9 + k];
      }
    }
#pragma unroll
    for (int cc = 0; cc < G; ++cc)
      y1[(((size_t)b * C_ + c0 + cc) * HW_) + h * W_ + wcol] = acc[cc];
  }
}

// ---------------- K4: pointwise GEMM C->O + hard-swish ----------------
// thread = 4 pixels x 16 outputs; weights pre-transposed to wt[c][o]
__global__ __launch_bounds__(TPB) void k_pwO(const float* __restrict__ y1,
                                             const float* __restrict__ wt,
                                             float* __restrict__ out) {
  int pi = blockIdx.x * TPB + threadIdx.x;  // 4-pixel group index
  int o0 = blockIdx.y * 16;
  int b = blockIdx.z;
  if (pi >= HW_ / 4) return;
  const float4* yp = (const float4*)(y1 + (size_t)b * C_ * HW_) + pi;
  float4 acc[16];
#pragma unroll
  for (int j = 0; j < 16; ++j) acc[j] = make_float4(0.f, 0.f, 0.f, 0.f);
  for (int c = 0; c < C_; ++c) {
    float4 v = yp[c * (HW_ / 4)];
    const float4* wv = (const float4*)(wt + c * O_ + o0);
    float wr[16];
    float4 w0 = wv[0], w1 = wv[1], w2 = wv[2], w3 = wv[3];
    wr[0] = w0.x; wr[1] = w0.y; wr[2] = w0.z; wr[3] = w0.w;
    wr[4] = w1.x; wr[5] = w1.y; wr[6] = w1.z; wr[7] = w1.w;
    wr[8] = w2.x; wr[9] = w2.y; wr[10] = w2.z; wr[11] = w2.w;
    wr[12] = w3.x; wr[13] = w3.y; wr[14] = w3.z; wr[15] = w3.w;
#pragma unroll
    for (int j = 0; j < 16; ++j) {
      acc[j].x += wr[j] * v.x;
      acc[j].y += wr[j] * v.y;
      acc[j].z += wr[j] * v.z;
      acc[j].w += wr[j] * v.w;
    }
  }
#pragma unroll
  for (int j = 0; j < 16; ++j) {
    float4 a = acc[j];
    float4 r;
    r.x = a.x * fminf(fmaxf(a.x + 3.f, 0.f), 6.f) * (1.f / 6.f);
    r.y = a.y * fminf(fmaxf(a.y + 3.f, 0.f), 6.f) * (1.f / 6.f);
    r.z = a.z * fminf(fmaxf(a.z + 3.f, 0.f), 6.f) * (1.f / 6.f);
    r.w = a.w * fminf(fmaxf(a.w + 3.f, 0.f), 6.f) * (1.f / 6.f);
    float4* outp = (float4*)(out + ((size_t)b * O_ + o0 + j) * HW_) + pi;
    *outp = r;
  }
}

extern "C" void kernel_launch(void* const* d_in, const int* in_sizes, int n_in,
                              void* d_out, int out_size, void* d_ws, size_t ws_size,
                              hipStream_t stream) {
  const float* x = (const float*)d_in[0];
  const float* og_dw = (const float*)d_in[1];
  const float* og_pw = (const float*)d_in[2];
  const float* dcn_w = (const float*)d_in[3];
  const float* pw_w = (const float*)d_in[4];
  float* out = (float*)d_out;

  float* ws = (float*)d_ws;
  float* t1 = ws;                                   // B*C*HW = 4,816,896
  float* offp = t1 + (size_t)B_ * C_ * HW_;         // B*18*HW = 451,584
  float* y1 = offp + (size_t)B_ * NOFF * HW_;       // B*C*HW = 4,816,896
  float* wt = y1 + (size_t)B_ * C_ * HW_;           // C*O = 73,728

  k_wt<<<(O_ * C_ + TPB - 1) / TPB, TPB, 0, stream>>>(pw_w, wt);
  k_dw<<<(B_ * C_ * HW_ + TPB - 1) / TPB, TPB, 0, stream>>>(x, og_dw, t1);
  k_pw18<<<(B_ * NOFF * (HW_ / 4)) / TPB, TPB, 0, stream>>>(t1, og_pw, offp);
  k_deform<<<dim3(H_ / 8, C_ / 8, B_), TPB, 0, stream>>>(x, offp, dcn_w, y1);
  k_pwO<<<dim3(4, O_ / 16, B_), TPB, 0, stream>>>(y1, wt, out);
}

// Round 2
// 133.399 us; speedup vs baseline: 1.2128x; 1.2128x over previous
//
#include <hip/hip_runtime.h>

#define TPB 256
constexpr int B_ = 8, C_ = 192, H_ = 56, W_ = 56, O_ = 384;
constexpr int HW_ = H_ * W_;          // 3136
constexpr int NOFF = 18;              // 9 taps * 2 (dy,dx)
constexpr int NPIX = B_ * HW_;        // 25088 = 196 * 128

typedef __attribute__((ext_vector_type(8))) short short8v;
typedef __attribute__((ext_vector_type(4))) float f32x4;

__device__ inline short f2bf(float f) {
  unsigned u = __builtin_bit_cast(unsigned, f);
  unsigned r = (u + 0x7fffu + ((u >> 16) & 1u)) >> 16;
  return (short)r;
}

// ---------------- K0: pw_w (O,C) fp32 -> bf16 same layout ----------------
__global__ __launch_bounds__(TPB) void k_wb(const float* __restrict__ pw,
                                            short* __restrict__ wtb) {
  int i = blockIdx.x * TPB + threadIdx.x;
  if (i < O_ * C_) wtb[i] = f2bf(pw[i]);
}

// ---------------- K1: depthwise 3x3, pad 1 ----------------
__global__ __launch_bounds__(TPB) void k_dw(const float* __restrict__ x,
                                            const float* __restrict__ wdw,
                                            float* __restrict__ t1) {
  int idx = blockIdx.x * TPB + threadIdx.x;
  if (idx >= B_ * C_ * HW_) return;
  int w = idx % W_;
  int h = (idx / W_) % H_;
  int c = (idx / HW_) % C_;
  const float* wp = wdw + c * 9;
  float acc = 0.f;
#pragma unroll
  for (int i = 0; i < 3; ++i) {
    int hh = h + i - 1;
    if ((unsigned)hh >= (unsigned)H_) continue;
#pragma unroll
    for (int j = 0; j < 3; ++j) {
      int ww = w + j - 1;
      if ((unsigned)ww >= (unsigned)W_) continue;
      acc += x[idx + (i - 1) * W_ + (j - 1)] * wp[i * 3 + j];
    }
  }
  t1[idx] = acc;
}

// ---------------- K2: pointwise C->18 + clip ----------------
__global__ __launch_bounds__(TPB) void k_pw18(const float* __restrict__ t1,
                                              const float* __restrict__ wpw,
                                              float* __restrict__ offp) {
  int idx = blockIdx.x * TPB + threadIdx.x;
  int q = idx % (HW_ / 4);
  int ch = (idx / (HW_ / 4)) % NOFF;
  int b = idx / (NOFF * (HW_ / 4));
  const float4* tp = (const float4*)(t1 + (size_t)b * C_ * HW_) + q;
  const float* wp = wpw + ch * C_;
  float4 acc = make_float4(0.f, 0.f, 0.f, 0.f);
  for (int c = 0; c < C_; ++c) {
    float4 v = tp[c * (HW_ / 4)];
    float wv = wp[c];
    acc.x += v.x * wv; acc.y += v.y * wv;
    acc.z += v.z * wv; acc.w += v.w * wv;
  }
  float4 r;
  r.x = fminf(fmaxf(acc.x, -1.f), 1.f);
  r.y = fminf(fmaxf(acc.y, -1.f), 1.f);
  r.z = fminf(fmaxf(acc.z, -1.f), 1.f);
  r.w = fminf(fmaxf(acc.w, -1.f), 1.f);
  float4* op = (float4*)(offp + ((size_t)b * NOFF + ch) * HW_) + q;
  *op = r;
}

// ---------------- K3: deformable sample + dcn 9-tap reduce ----------------
// writes y1t[pixel][c] in bf16 (pixel = b*HW + h*W + w)
__global__ __launch_bounds__(TPB) void k_deform(const float* __restrict__ x,
                                                const float* __restrict__ offp,
                                                const float* __restrict__ dcn,
                                                short* __restrict__ y1t) {
  constexpr int ROWS = 8, LR = 13, LW = 64, G = 8;
  __shared__ float sx[G * LR * LW];   // 26.6 KB
  int r0 = blockIdx.x * ROWS;
  int c0 = blockIdx.y * G;
  int b = blockIdx.z;
  int tid = threadIdx.x;

  for (int t = tid; t < G * LR * LW; t += TPB) {
    int cc = t / (LR * LW);
    int rem = t - cc * (LR * LW);
    int r = rem >> 6;
    int lx = rem & 63;
    int gy = r0 - 2 + r;
    int gx = lx - 2;
    float v = 0.f;
    if ((unsigned)gy < (unsigned)H_ && (unsigned)gx < (unsigned)W_)
      v = x[(((size_t)b * C_ + c0 + cc) * H_ + gy) * W_ + gx];
    sx[t] = v;
  }
  __syncthreads();

  for (int p = tid; p < ROWS * W_; p += TPB) {
    int hl = p / W_;
    int wcol = p - hl * W_;
    int h = r0 + hl;
    const float* op = offp + (size_t)b * NOFF * HW_ + h * W_ + wcol;
    float acc[G];
#pragma unroll
    for (int cc = 0; cc < G; ++cc) acc[cc] = 0.f;
#pragma unroll
    for (int k = 0; k < 9; ++k) {
      float dy = op[(2 * k) * HW_];
      float dx = op[(2 * k + 1) * HW_];
      float ys = (float)(h + k / 3 - 1) + dy;
      float xs = (float)(wcol + k % 3 - 1) + dx;
      float y0f = floorf(ys), x0f = floorf(xs);
      float ty = ys - y0f, tx = xs - x0f;
      int y0 = (int)y0f, x0 = (int)x0f;
      float omty = 1.f - ty, omtx = 1.f - tx;
      float w00 = omty * omtx, w01 = omty * tx;
      float w10 = ty * omtx, w11 = ty * tx;
      int base = (y0 - (r0 - 2)) * LW + (x0 + 2);
#pragma unroll
      for (int cc = 0; cc < G; ++cc) {
        const float* sp = sx + cc * (LR * LW) + base;
        float v00 = sp[0], v01 = sp[1], v10 = sp[LW], v11 = sp[LW + 1];
        float s = w00 * v00 + w01 * v01 + w10 * v10 + w11 * v11;
        acc[cc] += s * dcn[(c0 + cc) * 9 + k];
      }
    }
    short8v pk;
#pragma unroll
    for (int cc = 0; cc < G; ++cc) pk[cc] = f2bf(acc[cc]);
    *(short8v*)(y1t + ((size_t)b * HW_ + h * W_ + wcol) * C_ + c0) = pk;
  }
}

// ---------------- K4: MFMA bf16 GEMM  out[o][p] = sum_c wt[o][c]*y1t[p][c] ----
// grid: x = pixel-tile of 128 (196), y = o-tile of 64 (6). 4 waves, each 64x32.
__global__ __launch_bounds__(TPB) void k_gemm(const short* __restrict__ y1t,
                                              const short* __restrict__ wtb,
                                              float* __restrict__ out) {
  int wid = threadIdx.x >> 6;
  int lane = threadIdx.x & 63;
  int col = lane & 15;
  int kg = lane >> 4;
  int n0 = blockIdx.x * 128 + wid * 32;
  int m0 = blockIdx.y * 64;

  f32x4 acc[4][2];
#pragma unroll
  for (int mf = 0; mf < 4; ++mf)
#pragma unroll
    for (int nf = 0; nf < 2; ++nf) acc[mf][nf] = (f32x4){0.f, 0.f, 0.f, 0.f};

#pragma unroll
  for (int k0 = 0; k0 < C_; k0 += 32) {
    short8v a[4], b[2];
#pragma unroll
    for (int mf = 0; mf < 4; ++mf)
      a[mf] = *(const short8v*)(wtb + (m0 + mf * 16 + col) * C_ + k0 + kg * 8);
#pragma unroll
    for (int nf = 0; nf < 2; ++nf)
      b[nf] = *(const short8v*)(y1t + (size_t)(n0 + nf * 16 + col) * C_ + k0 + kg * 8);
#pragma unroll
    for (int mf = 0; mf < 4; ++mf)
#pragma unroll
      for (int nf = 0; nf < 2; ++nf)
        acc[mf][nf] = __builtin_amdgcn_mfma_f32_16x16x32_bf16(a[mf], b[nf], acc[mf][nf], 0, 0, 0);
  }

#pragma unroll
  for (int mf = 0; mf < 4; ++mf) {
#pragma unroll
    for (int nf = 0; nf < 2; ++nf) {
      int p = n0 + nf * 16 + col;
      int bb = p / HW_;
      int hw = p - bb * HW_;
#pragma unroll
      for (int reg = 0; reg < 4; ++reg) {
        int o = m0 + mf * 16 + kg * 4 + reg;
        float a = acc[mf][nf][reg];
        float r = a * fminf(fmaxf(a + 3.f, 0.f), 6.f) * (1.f / 6.f);
        out[((size_t)bb * O_ + o) * HW_ + hw] = r;
      }
    }
  }
}

extern "C" void kernel_launch(void* const* d_in, const int* in_sizes, int n_in,
                              void* d_out, int out_size, void* d_ws, size_t ws_size,
                              hipStream_t stream) {
  const float* x = (const float*)d_in[0];
  const float* og_dw = (const float*)d_in[1];
  const float* og_pw = (const float*)d_in[2];
  const float* dcn_w = (const float*)d_in[3];
  const float* pw_w = (const float*)d_in[4];
  float* out = (float*)d_out;

  float* ws = (float*)d_ws;
  float* t1 = ws;                                   // B*C*HW fp32
  float* offp = t1 + (size_t)B_ * C_ * HW_;         // B*18*HW fp32
  short* y1t = (short*)(offp + (size_t)B_ * NOFF * HW_);  // NPIX*C bf16
  short* wtb = y1t + (size_t)NPIX * C_;             // O*C bf16

  k_wb<<<(O_ * C_ + TPB - 1) / TPB, TPB, 0, stream>>>(pw_w, wtb);
  k_dw<<<(B_ * C_ * HW_ + TPB - 1) / TPB, TPB, 0, stream>>>(x, og_dw, t1);
  k_pw18<<<(B_ * NOFF * (HW_ / 4)) / TPB, TPB, 0, stream>>>(t1, og_pw, offp);
  k_deform<<<dim3(H_ / 8, C_ / 8, B_), TPB, 0, stream>>>(x, offp, dcn_w, y1t);
  k_gemm<<<dim3(NPIX / 128, O_ / 64), TPB, 0, stream>>>(y1t, wtb, out);
}

// Round 3
// 125.639 us; speedup vs baseline: 1.2878x; 1.0618x over previous
//
#include <hip/hip_runtime.h>

#define TPB 256
constexpr int B_ = 8, C_ = 192, H_ = 56, W_ = 56, O_ = 384;
constexpr int HW_ = H_ * W_;          // 3136
constexpr int NOFF = 18;              // 9 taps * 2 (dy,dx)
constexpr int NPIX = B_ * HW_;        // 25088 = 196 * 128

typedef __attribute__((ext_vector_type(8))) short short8v;
typedef __attribute__((ext_vector_type(4))) float f32x4;

__device__ inline unsigned short f2bf(float f) {
  unsigned u = __builtin_bit_cast(unsigned, f);
  unsigned r = (u + 0x7fffu + ((u >> 16) & 1u)) >> 16;
  return (unsigned short)r;
}
__device__ inline float bflo(unsigned u) {
  return __builtin_bit_cast(float, u << 16);
}
__device__ inline float bfhi(unsigned u) {
  return __builtin_bit_cast(float, u & 0xffff0000u);
}

// ---------------- K0: pw_w (O,C) fp32 -> bf16 same layout ----------------
__global__ __launch_bounds__(TPB) void k_wb(const float* __restrict__ pw,
                                            unsigned short* __restrict__ wtb) {
  int i = blockIdx.x * TPB + threadIdx.x;
  if (i < O_ * C_) wtb[i] = f2bf(pw[i]);
}

// ---------------- K1: depthwise 3x3, pad 1 ----------------
__global__ __launch_bounds__(TPB) void k_dw(const float* __restrict__ x,
                                            const float* __restrict__ wdw,
                                            float* __restrict__ t1) {
  int idx = blockIdx.x * TPB + threadIdx.x;
  if (idx >= B_ * C_ * HW_) return;
  int w = idx % W_;
  int h = (idx / W_) % H_;
  int c = (idx / HW_) % C_;
  const float* wp = wdw + c * 9;
  float acc = 0.f;
#pragma unroll
  for (int i = 0; i < 3; ++i) {
    int hh = h + i - 1;
    if ((unsigned)hh >= (unsigned)H_) continue;
#pragma unroll
    for (int j = 0; j < 3; ++j) {
      int ww = w + j - 1;
      if ((unsigned)ww >= (unsigned)W_) continue;
      acc += x[idx + (i - 1) * W_ + (j - 1)] * wp[i * 3 + j];
    }
  }
  t1[idx] = acc;
}

// ---------------- K2: pointwise C->18 + clip ----------------
__global__ __launch_bounds__(TPB) void k_pw18(const float* __restrict__ t1,
                                              const float* __restrict__ wpw,
                                              float* __restrict__ offp) {
  int idx = blockIdx.x * TPB + threadIdx.x;
  int q = idx % (HW_ / 4);
  int ch = (idx / (HW_ / 4)) % NOFF;
  int b = idx / (NOFF * (HW_ / 4));
  const float4* tp = (const float4*)(t1 + (size_t)b * C_ * HW_) + q;
  const float* wp = wpw + ch * C_;
  float4 acc = make_float4(0.f, 0.f, 0.f, 0.f);
  for (int c = 0; c < C_; ++c) {
    float4 v = tp[c * (HW_ / 4)];
    float wv = wp[c];
    acc.x += v.x * wv; acc.y += v.y * wv;
    acc.z += v.z * wv; acc.w += v.w * wv;
  }
  float4 r;
  r.x = fminf(fmaxf(acc.x, -1.f), 1.f);
  r.y = fminf(fmaxf(acc.y, -1.f), 1.f);
  r.z = fminf(fmaxf(acc.z, -1.f), 1.f);
  r.w = fminf(fmaxf(acc.w, -1.f), 1.f);
  float4* op = (float4*)(offp + ((size_t)b * NOFF + ch) * HW_) + q;
  *op = r;
}

// ---------------- K_XT: x[b][c][h][w] fp32 -> x_t[b][hw][c] bf16 ----------
// tile = 64 pixels x 192 channels, LDS transpose, padded stride 198 shorts.
__global__ __launch_bounds__(TPB) void k_xt(const float* __restrict__ x,
                                            unsigned short* __restrict__ xt) {
  __shared__ unsigned short tile[64 * 198];
  int tid = threadIdx.x;
  int P0 = blockIdx.x * 64;
  int b = blockIdx.y;
#pragma unroll
  for (int i = 0; i < 48; ++i) {
    int idx = i * TPB + tid;
    int px = idx & 63;
    int c = idx >> 6;
    float v = x[((size_t)(b * C_ + c)) * HW_ + P0 + px];
    tile[px * 198 + c] = f2bf(v);
  }
  __syncthreads();
  unsigned* xtu = (unsigned*)xt;
#pragma unroll
  for (int i = 0; i < 24; ++i) {
    int d = i * TPB + tid;            // dword index in 64*96
    int px = d / 96;
    int c2 = d - px * 96;
    unsigned v = *(const unsigned*)&tile[px * 198 + c2 * 2];
    xtu[((size_t)b * HW_ + P0 + px) * 96 + c2] = v;
  }
}

// ---------------- K3: deformable sample + dcn, channels-last --------------
// 16 lanes per pixel; lane owns 12 channels (3 reps x ushort4).
__global__ __launch_bounds__(TPB) void k_deform2(const unsigned short* __restrict__ xt,
                                                 const float* __restrict__ offp,
                                                 const float* __restrict__ dcn,
                                                 unsigned short* __restrict__ y1t) {
  __shared__ __align__(16) float dcnT[9 * C_];
  int tid = threadIdx.x;
  for (int t = tid; t < 9 * C_; t += TPB) {
    int k = t / C_, c = t - k * C_;
    dcnT[t] = dcn[c * 9 + k];
  }
  __syncthreads();

  int px = blockIdx.x * 16 + (tid >> 4);
  int lg = tid & 15;
  int b = px / HW_;
  int hw = px - b * HW_;
  int h = hw / W_;
  int w = hw - h * W_;
  const float* op = offp + (size_t)b * NOFF * HW_ + hw;
  float dyr[9], dxr[9];
#pragma unroll
  for (int k = 0; k < 9; ++k) {
    dyr[k] = op[(2 * k) * HW_];
    dxr[k] = op[(2 * k + 1) * HW_];
  }
  float acc[3][4];
#pragma unroll
  for (int r = 0; r < 3; ++r)
#pragma unroll
    for (int j = 0; j < 4; ++j) acc[r][j] = 0.f;

  int pb = b * HW_;
#pragma unroll
  for (int k = 0; k < 9; ++k) {
    const int ky = k / 3 - 1;
    const int kx = k - (k / 3) * 3 - 1;
    float ys = (float)(h + ky) + dyr[k];
    float xs = (float)(w + kx) + dxr[k];
    float y0f = floorf(ys), x0f = floorf(xs);
    float ty = ys - y0f, tx = xs - x0f;
    int y0 = (int)y0f, x0 = (int)x0f;
    int y1 = y0 + 1, x1 = x0 + 1;
    float fy0 = ((unsigned)y0 < (unsigned)H_) ? 1.f : 0.f;
    float fy1 = ((unsigned)y1 < (unsigned)H_) ? 1.f : 0.f;
    float fx0 = ((unsigned)x0 < (unsigned)W_) ? 1.f : 0.f;
    float fx1 = ((unsigned)x1 < (unsigned)W_) ? 1.f : 0.f;
    int y0c = y0 < 0 ? 0 : (y0 > H_ - 1 ? H_ - 1 : y0);
    int y1c = y1 < 0 ? 0 : (y1 > H_ - 1 ? H_ - 1 : y1);
    int x0c = x0 < 0 ? 0 : (x0 > W_ - 1 ? W_ - 1 : x0);
    int x1c = x1 < 0 ? 0 : (x1 > W_ - 1 ? W_ - 1 : x1);
    float omty = 1.f - ty, omtx = 1.f - tx;
    float w00 = omty * omtx * fy0 * fx0;
    float w01 = omty * tx * fy0 * fx1;
    float w10 = ty * omtx * fy1 * fx0;
    float w11 = ty * tx * fy1 * fx1;
    int r0 = (pb + y0c * W_) * C_;
    int r1 = (pb + y1c * W_) * C_;
    int p00 = r0 + x0c * C_, p01 = r0 + x1c * C_;
    int p10 = r1 + x0c * C_, p11 = r1 + x1c * C_;
#pragma unroll
    for (int rep = 0; rep < 3; ++rep) {
      int c0 = lg * 4 + rep * 64;
      uint2 u00 = *(const uint2*)(xt + p00 + c0);
      uint2 u01 = *(const uint2*)(xt + p01 + c0);
      uint2 u10 = *(const uint2*)(xt + p10 + c0);
      uint2 u11 = *(const uint2*)(xt + p11 + c0);
      f32x4 dw = *(const f32x4*)&dcnT[k * C_ + c0];
      float s0 = w00 * bflo(u00.x) + w01 * bflo(u01.x) + w10 * bflo(u10.x) + w11 * bflo(u11.x);
      float s1 = w00 * bfhi(u00.x) + w01 * bfhi(u01.x) + w10 * bfhi(u10.x) + w11 * bfhi(u11.x);
      float s2 = w00 * bflo(u00.y) + w01 * bflo(u01.y) + w10 * bflo(u10.y) + w11 * bflo(u11.y);
      float s3 = w00 * bfhi(u00.y) + w01 * bfhi(u01.y) + w10 * bfhi(u10.y) + w11 * bfhi(u11.y);
      acc[rep][0] += s0 * dw.x;
      acc[rep][1] += s1 * dw.y;
      acc[rep][2] += s2 * dw.z;
      acc[rep][3] += s3 * dw.w;
    }
  }
  int ob = px * C_ + lg * 4;
#pragma unroll
  for (int rep = 0; rep < 3; ++rep) {
    uint2 pk;
    pk.x = (unsigned)f2bf(acc[rep][0]) | ((unsigned)f2bf(acc[rep][1]) << 16);
    pk.y = (unsigned)f2bf(acc[rep][2]) | ((unsigned)f2bf(acc[rep][3]) << 16);
    *(uint2*)(y1t + ob + rep * 64) = pk;
  }
}

// ---------------- K4: MFMA bf16 GEMM  out[o][p] = sum_c wt[o][c]*y1t[p][c] ----
__global__ __launch_bounds__(TPB) void k_gemm(const unsigned short* __restrict__ y1t,
                                              const unsigned short* __restrict__ wtb,
                                              float* __restrict__ out) {
  int wid = threadIdx.x >> 6;
  int lane = threadIdx.x & 63;
  int col = lane & 15;
  int kg = lane >> 4;
  int n0 = blockIdx.x * 128 + wid * 32;
  int m0 = blockIdx.y * 64;

  f32x4 acc[4][2];
#pragma unroll
  for (int mf = 0; mf < 4; ++mf)
#pragma unroll
    for (int nf = 0; nf < 2; ++nf) acc[mf][nf] = (f32x4){0.f, 0.f, 0.f, 0.f};

#pragma unroll
  for (int k0 = 0; k0 < C_; k0 += 32) {
    short8v a[4], b[2];
#pragma unroll
    for (int mf = 0; mf < 4; ++mf)
      a[mf] = *(const short8v*)(wtb + (m0 + mf * 16 + col) * C_ + k0 + kg * 8);
#pragma unroll
    for (int nf = 0; nf < 2; ++nf)
      b[nf] = *(const short8v*)(y1t + (size_t)(n0 + nf * 16 + col) * C_ + k0 + kg * 8);
#pragma unroll
    for (int mf = 0; mf < 4; ++mf)
#pragma unroll
      for (int nf = 0; nf < 2; ++nf)
        acc[mf][nf] = __builtin_amdgcn_mfma_f32_16x16x32_bf16(a[mf], b[nf], acc[mf][nf], 0, 0, 0);
  }

#pragma unroll
  for (int mf = 0; mf < 4; ++mf) {
#pragma unroll
    for (int nf = 0; nf < 2; ++nf) {
      int p = n0 + nf * 16 + col;
      int bb = p / HW_;
      int hw = p - bb * HW_;
#pragma unroll
      for (int reg = 0; reg < 4; ++reg) {
        int o = m0 + mf * 16 + kg * 4 + reg;
        float a = acc[mf][nf][reg];
        float r = a * fminf(fmaxf(a + 3.f, 0.f), 6.f) * (1.f / 6.f);
        out[((size_t)bb * O_ + o) * HW_ + hw] = r;
      }
    }
  }
}

extern "C" void kernel_launch(void* const* d_in, const int* in_sizes, int n_in,
                              void* d_out, int out_size, void* d_ws, size_t ws_size,
                              hipStream_t stream) {
  const float* x = (const float*)d_in[0];
  const float* og_dw = (const float*)d_in[1];
  const float* og_pw = (const float*)d_in[2];
  const float* dcn_w = (const float*)d_in[3];
  const float* pw_w = (const float*)d_in[4];
  float* out = (float*)d_out;

  float* ws = (float*)d_ws;
  float* t1 = ws;                                        // B*C*HW fp32
  float* offp = t1 + (size_t)B_ * C_ * HW_;              // B*18*HW fp32
  unsigned short* y1t = (unsigned short*)(offp + (size_t)B_ * NOFF * HW_);
  unsigned short* wtb = y1t + (size_t)NPIX * C_;
  unsigned short* x_t = wtb + (size_t)O_ * C_;

  k_wb<<<(O_ * C_ + TPB - 1) / TPB, TPB, 0, stream>>>(pw_w, wtb);
  k_dw<<<(B_ * C_ * HW_ + TPB - 1) / TPB, TPB, 0, stream>>>(x, og_dw, t1);
  k_xt<<<dim3(HW_ / 64, B_), TPB, 0, stream>>>(x, x_t);
  k_pw18<<<(B_ * NOFF * (HW_ / 4)) / TPB, TPB, 0, stream>>>(t1, og_pw, offp);
  k_deform2<<<NPIX / 16, TPB, 0, stream>>>(x_t, offp, dcn_w, y1t);
  k_gemm<<<dim3(NPIX / 128, O_ / 64), TPB, 0, stream>>>(y1t, wtb, out);
}

// Round 4
// 125.499 us; speedup vs baseline: 1.2892x; 1.0011x over previous
//
#include <hip/hip_runtime.h>

#define TPB 256
constexpr int B_ = 8, C_ = 192, H_ = 56, W_ = 56, O_ = 384;
constexpr int HW_ = H_ * W_;          // 3136
constexpr int NOFF = 18;              // 9 taps * 2 (dy,dx)
constexpr int NPIX = B_ * HW_;        // 25088 = 196 * 128

typedef __attribute__((ext_vector_type(8))) short short8v;
typedef __attribute__((ext_vector_type(4))) float f32x4;

__device__ inline unsigned short f2bf(float f) {
  unsigned u = __builtin_bit_cast(unsigned, f);
  unsigned r = (u + 0x7fffu + ((u >> 16) & 1u)) >> 16;
  return (unsigned short)r;
}
__device__ inline float bflo(unsigned u) {
  return __builtin_bit_cast(float, u << 16);
}
__device__ inline float bfhi(unsigned u) {
  return __builtin_bit_cast(float, u & 0xffff0000u);
}

// ---------------- K0: pw_w (O,C) fp32 -> bf16 same layout ----------------
__global__ __launch_bounds__(TPB) void k_wb(const float* __restrict__ pw,
                                            unsigned short* __restrict__ wtb) {
  int i = blockIdx.x * TPB + threadIdx.x;
  if (i < O_ * C_) wtb[i] = f2bf(pw[i]);
}

// ---------------- K1: depthwise 3x3, pad 1 ----------------
__global__ __launch_bounds__(TPB) void k_dw(const float* __restrict__ x,
                                            const float* __restrict__ wdw,
                                            float* __restrict__ t1) {
  int idx = blockIdx.x * TPB + threadIdx.x;
  if (idx >= B_ * C_ * HW_) return;
  int w = idx % W_;
  int h = (idx / W_) % H_;
  int c = (idx / HW_) % C_;
  const float* wp = wdw + c * 9;
  float acc = 0.f;
#pragma unroll
  for (int i = 0; i < 3; ++i) {
    int hh = h + i - 1;
    if ((unsigned)hh >= (unsigned)H_) continue;
#pragma unroll
    for (int j = 0; j < 3; ++j) {
      int ww = w + j - 1;
      if ((unsigned)ww >= (unsigned)W_) continue;
      acc += x[idx + (i - 1) * W_ + (j - 1)] * wp[i * 3 + j];
    }
  }
  t1[idx] = acc;
}

// ---------------- K2: pointwise C->18 + clip ----------------
__global__ __launch_bounds__(TPB) void k_pw18(const float* __restrict__ t1,
                                              const float* __restrict__ wpw,
                                              float* __restrict__ offp) {
  int idx = blockIdx.x * TPB + threadIdx.x;
  int q = idx % (HW_ / 4);
  int ch = (idx / (HW_ / 4)) % NOFF;
  int b = idx / (NOFF * (HW_ / 4));
  const float4* tp = (const float4*)(t1 + (size_t)b * C_ * HW_) + q;
  const float* wp = wpw + ch * C_;
  float4 acc = make_float4(0.f, 0.f, 0.f, 0.f);
  for (int c = 0; c < C_; ++c) {
    float4 v = tp[c * (HW_ / 4)];
    float wv = wp[c];
    acc.x += v.x * wv; acc.y += v.y * wv;
    acc.z += v.z * wv; acc.w += v.w * wv;
  }
  float4 r;
  r.x = fminf(fmaxf(acc.x, -1.f), 1.f);
  r.y = fminf(fmaxf(acc.y, -1.f), 1.f);
  r.z = fminf(fmaxf(acc.z, -1.f), 1.f);
  r.w = fminf(fmaxf(acc.w, -1.f), 1.f);
  float4* op = (float4*)(offp + ((size_t)b * NOFF + ch) * HW_) + q;
  *op = r;
}

// ---------------- K_XT: x[b][c][h][w] fp32 -> x_t[b][hw][c] bf16 ----------
__global__ __launch_bounds__(TPB) void k_xt(const float* __restrict__ x,
                                            unsigned short* __restrict__ xt) {
  __shared__ unsigned short tile[64 * 198];
  int tid = threadIdx.x;
  int P0 = blockIdx.x * 64;
  int b = blockIdx.y;
#pragma unroll
  for (int i = 0; i < 48; ++i) {
    int idx = i * TPB + tid;
    int px = idx & 63;
    int c = idx >> 6;
    float v = x[((size_t)(b * C_ + c)) * HW_ + P0 + px];
    tile[px * 198 + c] = f2bf(v);
  }
  __syncthreads();
  unsigned* xtu = (unsigned*)xt;
#pragma unroll
  for (int i = 0; i < 24; ++i) {
    int d = i * TPB + tid;            // dword index in 64*96
    int px = d / 96;
    int c2 = d - px * 96;
    unsigned v = *(const unsigned*)&tile[px * 198 + c2 * 2];
    xtu[((size_t)b * HW_ + P0 + px) * 96 + c2] = v;
  }
}

// ---------------- K3: deform sample + dcn, addr-precompute + MLP ----------
// 16 lanes per pixel; lane owns 12 channels (3 reps x 4ch). All 9 taps'
// addresses+weights precomputed; rep-outer loop exposes 36 independent
// gathers per rep for software pipelining.
__global__ __launch_bounds__(TPB) void k_deform3(const unsigned short* __restrict__ xt,
                                                 const float* __restrict__ offp,
                                                 const float* __restrict__ dcn,
                                                 unsigned short* __restrict__ y1t) {
  __shared__ __align__(16) float dcnT[9 * C_];
  int tid = threadIdx.x;
  for (int t = tid; t < 9 * C_; t += TPB) {
    int k = t / C_, c = t - k * C_;
    dcnT[t] = dcn[c * 9 + k];
  }
  __syncthreads();

  int px = blockIdx.x * 16 + (tid >> 4);
  int lg = tid & 15;
  int b = px / HW_;
  int hw = px - b * HW_;
  int h = hw / W_;
  int w = hw - h * W_;
  const float* op = offp + (size_t)b * NOFF * HW_ + hw;

  int pA[9], pB[9], pC[9], pD[9];
  float wA[9], wB[9], wC[9], wD[9];
  int pb = b * HW_;
#pragma unroll
  for (int k = 0; k < 9; ++k) {
    float dy = op[(2 * k) * HW_];
    float dx = op[(2 * k + 1) * HW_];
    const int ky = k / 3 - 1;
    const int kx = k - (k / 3) * 3 - 1;
    float ys = (float)(h + ky) + dy;
    float xs = (float)(w + kx) + dx;
    float y0f = floorf(ys), x0f = floorf(xs);
    float ty = ys - y0f, tx = xs - x0f;
    int y0 = (int)y0f, x0 = (int)x0f;
    int y1 = y0 + 1, x1 = x0 + 1;
    float fy0 = ((unsigned)y0 < (unsigned)H_) ? 1.f : 0.f;
    float fy1 = ((unsigned)y1 < (unsigned)H_) ? 1.f : 0.f;
    float fx0 = ((unsigned)x0 < (unsigned)W_) ? 1.f : 0.f;
    float fx1 = ((unsigned)x1 < (unsigned)W_) ? 1.f : 0.f;
    int y0c = y0 < 0 ? 0 : (y0 > H_ - 1 ? H_ - 1 : y0);
    int y1c = y1 < 0 ? 0 : (y1 > H_ - 1 ? H_ - 1 : y1);
    int x0c = x0 < 0 ? 0 : (x0 > W_ - 1 ? W_ - 1 : x0);
    int x1c = x1 < 0 ? 0 : (x1 > W_ - 1 ? W_ - 1 : x1);
    float omty = 1.f - ty, omtx = 1.f - tx;
    wA[k] = omty * omtx * fy0 * fx0;
    wB[k] = omty * tx * fy0 * fx1;
    wC[k] = ty * omtx * fy1 * fx0;
    wD[k] = ty * tx * fy1 * fx1;
    int r0 = (pb + y0c * W_) * C_;
    int r1 = (pb + y1c * W_) * C_;
    pA[k] = r0 + x0c * C_;
    pB[k] = r0 + x1c * C_;
    pC[k] = r1 + x0c * C_;
    pD[k] = r1 + x1c * C_;
  }

  float acc[3][4];
#pragma unroll
  for (int r = 0; r < 3; ++r)
#pragma unroll
    for (int j = 0; j < 4; ++j) acc[r][j] = 0.f;

#pragma unroll
  for (int rep = 0; rep < 3; ++rep) {
    int c0 = lg * 4 + rep * 64;
#pragma unroll
    for (int k = 0; k < 9; ++k) {
      uint2 u00 = *(const uint2*)(xt + pA[k] + c0);
      uint2 u01 = *(const uint2*)(xt + pB[k] + c0);
      uint2 u10 = *(const uint2*)(xt + pC[k] + c0);
      uint2 u11 = *(const uint2*)(xt + pD[k] + c0);
      f32x4 dw = *(const f32x4*)&dcnT[k * C_ + c0];
      float s0 = wA[k] * bflo(u00.x) + wB[k] * bflo(u01.x) + wC[k] * bflo(u10.x) + wD[k] * bflo(u11.x);
      float s1 = wA[k] * bfhi(u00.x) + wB[k] * bfhi(u01.x) + wC[k] * bfhi(u10.x) + wD[k] * bfhi(u11.x);
      float s2 = wA[k] * bflo(u00.y) + wB[k] * bflo(u01.y) + wC[k] * bflo(u10.y) + wD[k] * bflo(u11.y);
      float s3 = wA[k] * bfhi(u00.y) + wB[k] * bfhi(u01.y) + wC[k] * bfhi(u10.y) + wD[k] * bfhi(u11.y);
      acc[rep][0] += s0 * dw.x;
      acc[rep][1] += s1 * dw.y;
      acc[rep][2] += s2 * dw.z;
      acc[rep][3] += s3 * dw.w;
    }
  }
  int ob = px * C_ + lg * 4;
#pragma unroll
  for (int rep = 0; rep < 3; ++rep) {
    uint2 pk;
    pk.x = (unsigned)f2bf(acc[rep][0]) | ((unsigned)f2bf(acc[rep][1]) << 16);
    pk.y = (unsigned)f2bf(acc[rep][2]) | ((unsigned)f2bf(acc[rep][3]) << 16);
    *(uint2*)(y1t + ob + rep * 64) = pk;
  }
}

// ---------------- K4: MFMA bf16 GEMM with LDS-staged, swizzled B-tile -----
// out[o][p] = sum_c wt[o][c] * y1t[p][c]; tile 64o x 128px, 4 waves.
__global__ __launch_bounds__(TPB) void k_gemm2(const unsigned short* __restrict__ y1t,
                                               const unsigned short* __restrict__ wtb,
                                               float* __restrict__ out) {
  __shared__ __align__(16) unsigned short bsm[128 * 192];  // 48 KB
  int tid = threadIdx.x;
  int n0 = blockIdx.x * 128;
  int m0 = blockIdx.y * 64;

  // stage B-tile: contiguous 48KB from y1t; store with row-XOR swizzle
  const char* gsrc = (const char*)(y1t + (size_t)n0 * C_);
  char* sbase = (char*)bsm;
#pragma unroll
  for (int r = 0; r < 12; ++r) {
    int L = (r * TPB + tid) * 16;
    int row = L / 384;
    int cb = L - row * 384;
    uint4 v = *(const uint4*)(gsrc + row * 384 + cb);
    *(uint4*)(sbase + (row * 384 + (cb ^ ((row & 7) << 4)))) = v;
  }
  __syncthreads();

  int wid = tid >> 6;
  int lane = tid & 63;
  int col = lane & 15;
  int kg = lane >> 4;

  f32x4 acc[4][2];
#pragma unroll
  for (int mf = 0; mf < 4; ++mf)
#pragma unroll
    for (int nf = 0; nf < 2; ++nf) acc[mf][nf] = (f32x4){0.f, 0.f, 0.f, 0.f};

#pragma unroll
  for (int k0 = 0; k0 < C_; k0 += 32) {
    short8v a[4], bfr[2];
#pragma unroll
    for (int mf = 0; mf < 4; ++mf)
      a[mf] = *(const short8v*)(wtb + (m0 + mf * 16 + col) * C_ + k0 + kg * 8);
#pragma unroll
    for (int nf = 0; nf < 2; ++nf) {
      int brow = wid * 32 + nf * 16 + col;
      int kb = (k0 + kg * 8) * 2;
      bfr[nf] = *(const short8v*)(sbase + brow * 384 + (kb ^ ((brow & 7) << 4)));
    }
#pragma unroll
    for (int mf = 0; mf < 4; ++mf)
#pragma unroll
      for (int nf = 0; nf < 2; ++nf)
        acc[mf][nf] = __builtin_amdgcn_mfma_f32_16x16x32_bf16(a[mf], bfr[nf], acc[mf][nf], 0, 0, 0);
  }

#pragma unroll
  for (int mf = 0; mf < 4; ++mf) {
#pragma unroll
    for (int nf = 0; nf < 2; ++nf) {
      int p = n0 + wid * 32 + nf * 16 + col;
      int bb = p / HW_;
      int hw = p - bb * HW_;
#pragma unroll
      for (int reg = 0; reg < 4; ++reg) {
        int o = m0 + mf * 16 + kg * 4 + reg;
        float a = acc[mf][nf][reg];
        float r = a * fminf(fmaxf(a + 3.f, 0.f), 6.f) * (1.f / 6.f);
        out[((size_t)bb * O_ + o) * HW_ + hw] = r;
      }
    }
  }
}

extern "C" void kernel_launch(void* const* d_in, const int* in_sizes, int n_in,
                              void* d_out, int out_size, void* d_ws, size_t ws_size,
                              hipStream_t stream) {
  const float* x = (const float*)d_in[0];
  const float* og_dw = (const float*)d_in[1];
  const float* og_pw = (const float*)d_in[2];
  const float* dcn_w = (const float*)d_in[3];
  const float* pw_w = (const float*)d_in[4];
  float* out = (float*)d_out;

  float* ws = (float*)d_ws;
  float* t1 = ws;                                        // B*C*HW fp32
  float* offp = t1 + (size_t)B_ * C_ * HW_;              // B*18*HW fp32
  unsigned short* y1t = (unsigned short*)(offp + (size_t)B_ * NOFF * HW_);
  unsigned short* wtb = y1t + (size_t)NPIX * C_;
  unsigned short* x_t = wtb + (size_t)O_ * C_;

  k_wb<<<(O_ * C_ + TPB - 1) / TPB, TPB, 0, stream>>>(pw_w, wtb);
  k_dw<<<(B_ * C_ * HW_ + TPB - 1) / TPB, TPB, 0, stream>>>(x, og_dw, t1);
  k_xt<<<dim3(HW_ / 64, B_), TPB, 0, stream>>>(x, x_t);
  k_pw18<<<(B_ * NOFF * (HW_ / 4)) / TPB, TPB, 0, stream>>>(t1, og_pw, offp);
  k_deform3<<<NPIX / 16, TPB, 0, stream>>>(x_t, offp, dcn_w, y1t);
  k_gemm2<<<dim3(NPIX / 128, O_ / 64), TPB, 0, stream>>>(y1t, wtb, out);
}